// Round 9
// baseline (153.217 us; speedup 1.0000x reference)
//
#include <hip/hip_runtime.h>

typedef __bf16 bf16x8 __attribute__((ext_vector_type(8)));
typedef float  f32x4  __attribute__((ext_vector_type(4)));

#define K_SCALE 0.25505402682247326f  // log2(e)/sqrt(32), folded into Wk/bk

static __device__ __forceinline__ unsigned short f2bf(float f) {
  return __builtin_bit_cast(unsigned short, (__bf16)f);
}
static __device__ __forceinline__ f32x4 mfma16(bf16x8 a, bf16x8 b, f32x4 c) {
  return __builtin_amdgcn_mfma_f32_16x16x32_bf16(a, b, c, 0, 0, 0);
}

// ---- prep2: X -> bf16 (row-major); W -> bf16 frag-order (K pre-scaled);
//      bias concat (bk pre-scaled). Grid 1121 x 256. -------------------------
__global__ __launch_bounds__(256) void prep_kernel(
    const float* __restrict__ X,
    const float* __restrict__ Wq, const float* __restrict__ bq,
    const float* __restrict__ Wk, const float* __restrict__ bk,
    const float* __restrict__ Wv, const float* __restrict__ bv,
    unsigned short* __restrict__ Xb, unsigned short* __restrict__ Wf,
    float* __restrict__ bias) {
  int blk = blockIdx.x;
  if (blk < 1024) {  // X: 4.19M f32 -> bf16, 16 elems/thread
    int idx = blk * 4096 + threadIdx.x * 16;
    const float4* src = reinterpret_cast<const float4*>(X + idx);
    float4 f0 = src[0], f1 = src[1], f2 = src[2], f3 = src[3];
    bf16x8 h0, h1;
    h0[0]=(__bf16)f0.x; h0[1]=(__bf16)f0.y; h0[2]=(__bf16)f0.z; h0[3]=(__bf16)f0.w;
    h0[4]=(__bf16)f1.x; h0[5]=(__bf16)f1.y; h0[6]=(__bf16)f1.z; h0[7]=(__bf16)f1.w;
    h1[0]=(__bf16)f2.x; h1[1]=(__bf16)f2.y; h1[2]=(__bf16)f2.z; h1[3]=(__bf16)f2.w;
    h1[4]=(__bf16)f3.x; h1[5]=(__bf16)f3.y; h1[6]=(__bf16)f3.z; h1[7]=(__bf16)f3.w;
    *reinterpret_cast<bf16x8*>(Xb + idx) = h0;
    *reinterpret_cast<bf16x8*>(Xb + idx + 8) = h1;
    return;
  }
  if (blk == 1120) {  // bias concat (bk scaled)
    int t = threadIdx.x;
#pragma unroll
    for (int kseg = 0; kseg < 3; ++kseg) {
      int i = kseg * 256 + t;
      float bb;
      if (i < 256)      bb = bq[i];
      else if (i < 512) bb = bk[i - 256] * K_SCALE;
      else              bb = bv[i - 512];
      bias[i] = bb;
    }
    return;
  }
  int fidx = (blk - 1024) * 256 + threadIdx.x;  // < 24576 frag entries
  int lane = fidx & 63;
  int ks = (fidx >> 6) & 7;
  int ct = fidx >> 9;   // 48 col-tiles: Q 0-15, K 16-31, V 32-47
  int n = ct * 16 + (lane & 15);
  int kk = ks * 32 + (lane >> 4) * 8;
  const float* src;
  float scale = 1.0f;
  if (n < 256)      src = Wq + n * 256 + kk;
  else if (n < 512) { src = Wk + (n - 256) * 256 + kk; scale = K_SCALE; }
  else              src = Wv + (n - 512) * 256 + kk;
  float4 f0 = reinterpret_cast<const float4*>(src)[0];
  float4 f1 = reinterpret_cast<const float4*>(src)[1];
  bf16x8 h;
  h[0] = (__bf16)(f0.x * scale); h[1] = (__bf16)(f0.y * scale);
  h[2] = (__bf16)(f0.z * scale); h[3] = (__bf16)(f0.w * scale);
  h[4] = (__bf16)(f1.x * scale); h[5] = (__bf16)(f1.y * scale);
  h[6] = (__bf16)(f1.z * scale); h[7] = (__bf16)(f1.w * scale);
  *reinterpret_cast<bf16x8*>(Wf + fidx * 8) = h;
}

// ---- fused: per-block head projection (K^T,V -> LDS; Q -> regs) + 4 attn
//      layers. Grid 512 = bh x 2 seg; 8 waves x (64 keys proj, 32 queries). --
__global__ __launch_bounds__(512, 4) void attn_kernel(
    const unsigned short* __restrict__ Xb, const unsigned short* __restrict__ Wf,
    const float* __restrict__ bias, float* __restrict__ Out) {
  __shared__ __align__(16) unsigned short Ks[16384];  // K [n][pd], R5 swizzle
  __shared__ __align__(16) unsigned short Vf[16384];  // V frag-order (R8 layout)
  const int tid = threadIdx.x;
  const int bh = blockIdx.x >> 1, seg = blockIdx.x & 1;
  const int b = bh >> 3, h = bh & 7;
  const int w = tid >> 6, lane = tid & 63, c = lane & 15, quad = lane >> 4;
  const f32x4 zf = {0.f, 0.f, 0.f, 0.f};
  // ---- K^T / V projection for keys kw..kw+63 (this wave's slice) ----
  const int kw = w * 64;
  f32x4 accK[2][4], accV[4][2];
#pragma unroll
  for (int dt = 0; dt < 2; ++dt)
#pragma unroll
    for (int kt = 0; kt < 4; ++kt) { accK[dt][kt] = zf; accV[kt][dt] = zf; }
#pragma unroll
  for (int ks = 0; ks < 8; ++ks) {
    bf16x8 bX[4];  // X key-rows frag (A and B layouts coincide)
#pragma unroll
    for (int kt = 0; kt < 4; ++kt)
      bX[kt] = *reinterpret_cast<const bf16x8*>(
          Xb + (b * 512 + kw + kt * 16 + c) * 256 + ks * 32 + quad * 8);
    bf16x8 aWk[2], aWv[2];
#pragma unroll
    for (int dt = 0; dt < 2; ++dt) {
      aWk[dt] = *reinterpret_cast<const bf16x8*>(
          Wf + (((16 + h * 2 + dt) * 8 + ks) * 64 + lane) * 8);
      aWv[dt] = *reinterpret_cast<const bf16x8*>(
          Wf + (((32 + h * 2 + dt) * 8 + ks) * 64 + lane) * 8);
    }
#pragma unroll
    for (int dt = 0; dt < 2; ++dt)
#pragma unroll
      for (int kt = 0; kt < 4; ++kt)
        accK[dt][kt] = mfma16(aWk[dt], bX[kt], accK[dt][kt]);  // D[d][key]
#pragma unroll
    for (int mt = 0; mt < 4; ++mt)
#pragma unroll
      for (int nt = 0; nt < 2; ++nt)
        accV[mt][nt] = mfma16(bX[mt], aWv[nt], accV[mt][nt]);  // D[key][d]
  }
  // K^T -> LDS [n][pd]: pd = quad*8 + dt*4 + r (r-consecutive -> ushort4)
#pragma unroll
  for (int dt = 0; dt < 2; ++dt) {
    f32x4 bk4 = *reinterpret_cast<const f32x4*>(bias + 256 + h * 32 + dt * 16 + quad * 4);
#pragma unroll
    for (int kt = 0; kt < 4; ++kt) {
      int n = kw + kt * 16 + c;
      int slot = quad ^ ((n >> 1) & 3);
      ushort4 pk;
      pk.x = f2bf(accK[dt][kt][0] + bk4[0]); pk.y = f2bf(accK[dt][kt][1] + bk4[1]);
      pk.z = f2bf(accK[dt][kt][2] + bk4[2]); pk.w = f2bf(accK[dt][kt][3] + bk4[3]);
      *reinterpret_cast<ushort4*>(&Ks[n * 32 + slot * 8 + dt * 4]) = pk;
    }
  }
  // V -> LDS frag-order: ch=w*2+(mt>>1), lane'=quad*16+c, j=(mt&1)*4+r
#pragma unroll
  for (int nt = 0; nt < 2; ++nt) {
    float bv1 = bias[512 + h * 32 + nt * 16 + c];
#pragma unroll
    for (int mt = 0; mt < 4; ++mt) {
      ushort4 pk;
      pk.x = f2bf(accV[mt][nt][0] + bv1); pk.y = f2bf(accV[mt][nt][1] + bv1);
      pk.z = f2bf(accV[mt][nt][2] + bv1); pk.w = f2bf(accV[mt][nt][3] + bv1);
      *reinterpret_cast<ushort4*>(
          &Vf[((w * 2 + (mt >> 1)) * 2 + nt) * 512 + (quad * 16 + c) * 8 + (mt & 1) * 4]) = pk;
    }
  }
  // ---- Q projection -> x registers (transposed-C layout) ----
  const int rowq = seg * 256 + w * 32;
  f32x4 x[2][2] = {{zf, zf}, {zf, zf}};  // query=rowq+rg*16+c, d=tt*16+quad*4+r
#pragma unroll
  for (int ks = 0; ks < 8; ++ks) {
    bf16x8 bXq[2], aQ[2];
#pragma unroll
    for (int rg = 0; rg < 2; ++rg)
      bXq[rg] = *reinterpret_cast<const bf16x8*>(
          Xb + (b * 512 + rowq + rg * 16 + c) * 256 + ks * 32 + quad * 8);
#pragma unroll
    for (int tt = 0; tt < 2; ++tt)
      aQ[tt] = *reinterpret_cast<const bf16x8*>(
          Wf + (((h * 2 + tt) * 8 + ks) * 64 + lane) * 8);
#pragma unroll
    for (int rg = 0; rg < 2; ++rg)
#pragma unroll
      for (int tt = 0; tt < 2; ++tt)
        x[rg][tt] = mfma16(aQ[tt], bXq[rg], x[rg][tt]);
  }
#pragma unroll
  for (int tt = 0; tt < 2; ++tt) {
    f32x4 bq4 = *reinterpret_cast<const f32x4*>(bias + h * 32 + tt * 16 + quad * 4);
#pragma unroll
    for (int rg = 0; rg < 2; ++rg) x[rg][tt] += bq4;
  }
  __syncthreads();  // only barrier: K/V visible to all waves
  // ---- 4 fused attention layers (R5/R8 verified structure) ----
  bf16x8 ones;
#pragma unroll
  for (int j = 0; j < 8; ++j) ones[j] = (__bf16)1.0f;
#pragma unroll 1
  for (int layer = 0; layer < 4; ++layer) {
    bf16x8 aq[2];
#pragma unroll
    for (int rg = 0; rg < 2; ++rg) {
      aq[rg][0] = (__bf16)x[rg][0][0]; aq[rg][1] = (__bf16)x[rg][0][1];
      aq[rg][2] = (__bf16)x[rg][0][2]; aq[rg][3] = (__bf16)x[rg][0][3];
      aq[rg][4] = (__bf16)x[rg][1][0]; aq[rg][5] = (__bf16)x[rg][1][1];
      aq[rg][6] = (__bf16)x[rg][1][2]; aq[rg][7] = (__bf16)x[rg][1][3];
    }
    f32x4 sacc[2] = {zf, zf};
    f32x4 O[2][2] = {{zf, zf}, {zf, zf}};
#pragma unroll 4
    for (int ch = 0; ch < 16; ++ch) {
      f32x4 S[2][2];  // S^T: row=key(quad*4+r), col=query(c)
#pragma unroll
      for (int tt = 0; tt < 2; ++tt) {
        int n = (ch * 2 + tt) * 16 + c;
        bf16x8 kf = *reinterpret_cast<const bf16x8*>(
            &Ks[n * 32 + ((quad ^ ((n >> 1) & 3)) << 3)]);
#pragma unroll
        for (int rg = 0; rg < 2; ++rg) S[rg][tt] = mfma16(kf, aq[rg], zf);
      }
      bf16x8 ap[2];
#pragma unroll
      for (int rg = 0; rg < 2; ++rg) {
#pragma unroll
        for (int tt = 0; tt < 2; ++tt)
#pragma unroll
          for (int r = 0; r < 4; ++r)
            S[rg][tt][r] = __builtin_amdgcn_exp2f(S[rg][tt][r]);
        ap[rg][0] = (__bf16)S[rg][0][0]; ap[rg][1] = (__bf16)S[rg][0][1];
        ap[rg][2] = (__bf16)S[rg][0][2]; ap[rg][3] = (__bf16)S[rg][0][3];
        ap[rg][4] = (__bf16)S[rg][1][0]; ap[rg][5] = (__bf16)S[rg][1][1];
        ap[rg][6] = (__bf16)S[rg][1][2]; ap[rg][7] = (__bf16)S[rg][1][3];
        sacc[rg] = mfma16(ones, ap[rg], sacc[rg]);  // denom on MFMA pipe
      }
#pragma unroll
      for (int tt = 0; tt < 2; ++tt) {
        bf16x8 vf = *reinterpret_cast<const bf16x8*>(
            &Vf[((ch * 2 + tt) * 64 + lane) * 8]);
#pragma unroll
        for (int rg = 0; rg < 2; ++rg) O[rg][tt] = mfma16(vf, ap[rg], O[rg][tt]);
      }
    }
#pragma unroll
    for (int rg = 0; rg < 2; ++rg) {
      float inv = __builtin_amdgcn_rcpf(sacc[rg][0]);  // every lane: own query
#pragma unroll
      for (int tt = 0; tt < 2; ++tt)
#pragma unroll
        for (int r = 0; r < 4; ++r) x[rg][tt][r] += O[rg][tt][r] * inv;
    }
  }
#pragma unroll
  for (int rg = 0; rg < 2; ++rg)
#pragma unroll
    for (int tt = 0; tt < 2; ++tt)
      *reinterpret_cast<f32x4*>(
          Out + (b * 512 + rowq + rg * 16 + c) * 256 + h * 32 + tt * 16 + quad * 4) = x[rg][tt];
}

extern "C" void kernel_launch(void* const* d_in, const int* in_sizes, int n_in,
                              void* d_out, int out_size, void* d_ws, size_t ws_size,
                              hipStream_t stream) {
  const float* X  = (const float*)d_in[0];
  const float* Wq = (const float*)d_in[1];
  const float* bq = (const float*)d_in[2];
  const float* Wk = (const float*)d_in[3];
  const float* bk = (const float*)d_in[4];
  const float* Wv = (const float*)d_in[5];
  const float* bv = (const float*)d_in[6];
  char* ws = (char*)d_ws;
  unsigned short* Wf   = (unsigned short*)(ws);            // 393216 B
  float*          bias = (float*)(ws + 393216);            // 3072 B
  unsigned short* Xb   = (unsigned short*)(ws + 397312);   // 8.39 MB bf16 X
  float* out = (float*)d_out;
  prep_kernel<<<1121, 256, 0, stream>>>(X, Wq, bq, Wk, bk, Wv, bv, Xb, Wf, bias);
  attn_kernel<<<512, 512, 0, stream>>>(Xb, Wf, bias, out);
}